// Round 7
// baseline (6448.273 us; speedup 1.0000x reference)
//
#include <hip/hip_runtime.h>
#include <math.h>

#define BB 16
#define NN 512   // seq1 rows = columns of the transposed LSA problem
#define MM 448   // seq2 rows = rows of the transposed LSA problem
#define DD 1536

// ---------------------------------------------------------------------------
// Cost kernel: Ct[b][j][i] = ||seq1[b,i,:] - seq2[b,j,:]||  (float32)
// R7 re-tile: 128x64 tile, 8x4 outputs/thread (i-set {ix4, ix4+64} keeps both
// ds_read_b128 at the verified 2-way bank pattern). Per-element FMA chains
// (k0 chunk order, kk order, f32 fmaf inner, f64 outer acc) are UNCHANGED ->
// Ct is bit-identical to all passing rounds. LDS bytes/FMA: 2.0 -> 1.5.
// ---------------------------------------------------------------------------
constexpr int TK = 32;

__global__ __launch_bounds__(256) void cost_kernel(const float* __restrict__ s1,
                                                   const float* __restrict__ s2,
                                                   float* __restrict__ Ct) {
  __shared__ float As[TK][132];   // 128 rows + pad
  __shared__ float Bs[TK][68];    // 64 rows + pad
  const int b = blockIdx.z;
  const int ibase = blockIdx.x * 128;
  const int jbase = blockIdx.y * 64;
  const int tid = threadIdx.x;
  const float* s1b = s1 + ((size_t)b * NN + ibase) * DD;
  const float* s2b = s2 + ((size_t)b * MM + jbase) * DD;
  const int ix4 = (tid & 15) * 4;          // first i-quad; second at +64
  const int jy = (tid >> 4) * 4;
  double acc[32];
#pragma unroll
  for (int t = 0; t < 32; ++t) acc[t] = 0.0;

  for (int k0 = 0; k0 < DD; k0 += TK) {
#pragma unroll
    for (int rep = 0; rep < 4; ++rep) {    // A: 128 rows x 32 k
      int idx = tid + rep * 256;
      int r = idx >> 3;
      int c4 = (idx & 7) * 4;
      float4 a = *(const float4*)(s1b + (size_t)r * DD + k0 + c4);
      As[c4 + 0][r] = a.x; As[c4 + 1][r] = a.y; As[c4 + 2][r] = a.z; As[c4 + 3][r] = a.w;
    }
#pragma unroll
    for (int rep = 0; rep < 2; ++rep) {    // B: 64 rows x 32 k
      int idx = tid + rep * 256;
      int r = idx >> 3;
      int c4 = (idx & 7) * 4;
      float4 bb = *(const float4*)(s2b + (size_t)r * DD + k0 + c4);
      Bs[c4 + 0][r] = bb.x; Bs[c4 + 1][r] = bb.y; Bs[c4 + 2][r] = bb.z; Bs[c4 + 3][r] = bb.w;
    }
    __syncthreads();
    float pacc[32];
#pragma unroll
    for (int t = 0; t < 32; ++t) pacc[t] = 0.f;
#pragma unroll 8
    for (int kk = 0; kk < TK; ++kk) {
      float4 av0 = *(const float4*)&As[kk][ix4];
      float4 av1 = *(const float4*)&As[kk][ix4 + 64];
      float4 bv = *(const float4*)&Bs[kk][jy];
      float a[8] = {av0.x, av0.y, av0.z, av0.w, av1.x, av1.y, av1.z, av1.w};
      float bq[4] = {bv.x, bv.y, bv.z, bv.w};
#pragma unroll
      for (int t = 0; t < 8; ++t)
#pragma unroll
        for (int q = 0; q < 4; ++q) {
          float d = a[t] - bq[q];
          pacc[t * 4 + q] = fmaf(d, d, pacc[t * 4 + q]);
        }
    }
#pragma unroll
    for (int t = 0; t < 32; ++t) acc[t] += (double)pacc[t];
    __syncthreads();
  }
#pragma unroll
  for (int t = 0; t < 8; ++t)
#pragma unroll
    for (int q = 0; q < 4; ++q) {
      int i = ibase + ((t < 4) ? (ix4 + t) : (64 + ix4 + t - 4));
      int jj = jbase + jy + q;
      float d2 = (float)acc[t * 4 + q];
      Ct[((size_t)b * MM + jj) * NN + i] = sqrtf(fmaxf(d2, 0.f));
    }
}

// ---------------------------------------------------------------------------
// Cross-lane reduction primitives (DPP shr 1/2/4/8 + bcast 15/31, readlane 63
// broadcast — control pattern verified bit-exact across passing rounds).
// ---------------------------------------------------------------------------
__device__ __forceinline__ unsigned wave_min_bcast_u32(unsigned x) {
  int v = (int)x;
#define ST(C) { int o = __builtin_amdgcn_update_dpp(-1, v, C, 0xF, 0xF, false); \
                v = ((unsigned)o < (unsigned)v) ? o : v; }
  ST(0x111) ST(0x112) ST(0x114) ST(0x118) ST(0x142) ST(0x143)
#undef ST
  return (unsigned)__builtin_amdgcn_readlane(v, 63);
}

// Exact f64 min over the wave for NONNEGATIVE doubles: bit pattern of a
// nonneg double is order-preserving as u64 -> two u32 min stages (hi, then
// lo among hi-winners). Verified bit-exact (R1/R5/R6 phase 2).
__device__ __forceinline__ double wave_min_bcast_f64_fast(double x) {
  union DU { double d; unsigned u[2]; };
  DU v; v.d = x;
  unsigned hmin = wave_min_bcast_u32(v.u[1]);
  unsigned lc = (v.u[1] == hmin) ? v.u[0] : 0xFFFFFFFFu;
  unsigned lmin = wave_min_bcast_u32(lc);
  DU r; r.u[0] = lmin; r.u[1] = hmin;
  return r.d;
}

__device__ __forceinline__ float wave_min_bcast_f32(float x) {
  union FU { float f; int i; };
  FU v; v.f = x;
  const int INFB = 0x7f7fffff;   // FLT_MAX bit pattern
#define DPP1(CTRL) { FU o; \
  o.i = __builtin_amdgcn_update_dpp(INFB, v.i, CTRL, 0xF, 0xF, false); \
  if (o.f < v.f) v.f = o.f; }
  DPP1(0x111) DPP1(0x112) DPP1(0x114) DPP1(0x118) DPP1(0x142) DPP1(0x143)
#undef DPP1
  FU r; r.i = __builtin_amdgcn_readlane(v.i, 63);
  return r.f;
}

// ---------------------------------------------------------------------------
// Full Jonker-Volgenant, ONE WAVE per batch.
// R7 = R6 with phase-2 passes 2 -> 4 (the ONLY jv change; isolates the
// R2/R4 [4-pass vs branchy-fastpath] confound). Correctness: R2/R4 ran
// exactly 4 passes with a phase-2 decision stream bit-identical to this
// code's (exact_min_sl == f64_fast + value-ballot for nonneg, no -0), and
// phase 3 here is decision-identical to R2's verified stream -> the final
// matching equals R2/R4's (absmax 0).
// ---------------------------------------------------------------------------
__global__ __launch_bounds__(64) void jv_kernel(const float* __restrict__ Ct,
                                                int* __restrict__ perm) {
  const int b = blockIdx.x;
  const float* C = Ct + (size_t)b * MM * NN;
  __shared__ double u_lds[MM + 1];
  __shared__ int p_lds[NN + 1];
  __shared__ int way_lds[NN + 1];
  __shared__ double rec_lds[NN + 1];
  __shared__ int preg_lds[NN + 1];
  __shared__ int colOwner[NN];
  __shared__ int rowMatched[MM];
  __shared__ int freeL[MM];
  __shared__ int nfree_s;
  __shared__ int cnt_lds[64];
  const int lane = threadIdx.x;
  const int jbase = 8 * lane + 1;   // owned columns, 1-based

  if (lane == 0) u_lds[0] = 0.0;
  for (int t = lane; t <= NN; t += 64) { p_lds[t] = 0; way_lds[t] = 0; }
  for (int t = lane; t < NN; t += 64) colOwner[t] = -1;
  for (int t = lane; t < MM; t += 64) rowMatched[t] = 0;
  asm volatile("s_waitcnt lgkmcnt(0)" ::: "memory");

  // ---- Phase 1: row reduction + greedy claim (depth-2 prefetch) ----
  {
    const float4* r40 = (const float4*)(C);
    const float4* r41 = (const float4*)(C + (size_t)NN);
    float4 ca = r40[2 * lane], cb = r40[2 * lane + 1];
    float4 na = r41[2 * lane], nb = r41[2 * lane + 1];
    for (int r = 0; r < MM; ++r) {
      int rp = (r + 2 < MM) ? (r + 2) : (MM - 1);
      const float4* r4n = (const float4*)(C + (size_t)rp * NN);
      float4 pa = r4n[2 * lane], pb = r4n[2 * lane + 1];
      float c[8] = {ca.x, ca.y, ca.z, ca.w, cb.x, cb.y, cb.z, cb.w};
      float lm = 1e30f; int la = 0;
#pragma unroll
      for (int q = 0; q < 8; ++q)
        if (c[q] < lm) { lm = c[q]; la = 8 * lane + q; }
      float rm = wave_min_bcast_f32(lm);
      unsigned long long bm = __ballot(lm == rm);
      int sl = (int)__ffsll((unsigned long long)bm) - 1;
      int jc = __builtin_amdgcn_readlane(la, sl);
      if (lane == 0) {
        u_lds[r + 1] = (double)rm;
        if (colOwner[jc] < 0) {
          colOwner[jc] = r;
          rowMatched[r] = 1;
          p_lds[jc + 1] = r + 1;
        }
      }
      ca = na; cb = nb; na = pa; nb = pb;
    }
  }
  double vcol[8];
#pragma unroll
  for (int q = 0; q < 8; ++q) vcol[q] = 0.0;
  asm volatile("s_waitcnt lgkmcnt(0)" ::: "memory");

  // ---- build free list (ascending) ----
  if (lane == 0) {
    int n = 0;
    for (int r = 0; r < MM; ++r) if (!rowMatched[r]) freeL[n++] = r;
    nfree_s = n;
  }
  asm volatile("s_waitcnt lgkmcnt(0)" ::: "memory");
  int nfree = nfree_s;   // same LDS addr in all lanes -> uniform

  // ---- Phase 2: augmenting row reduction, 4 passes (next-row prefetch) ----
  for (int pass = 0; pass < 4; ++pass) {
    int prev = nfree; nfree = 0; int k = 0;
    if (prev == 0) continue;
    int i = freeL[0];                                   // uniform LDS read
    {
      const float4* r4p = (const float4*)(C + (size_t)i * NN);
      float4 ca = r4p[2 * lane];
      float4 cb = r4p[2 * lane + 1];
      while (true) {
        const int kn = k + 1;
        const int ig = (kn < prev) ? freeL[kn] : 0;     // uniform prefetch guess
        const float4* r4n = (const float4*)(C + (size_t)ig * NN);
        float4 nca = r4n[2 * lane];
        float4 ncb = r4n[2 * lane + 1];

        float c[8] = {ca.x, ca.y, ca.z, ca.w, cb.x, cb.y, cb.z, cb.w};
        double m1 = 1e18, m2 = 1e18; int a1 = 0;
#pragma unroll
        for (int q = 0; q < 8; ++q) {
          double h = (double)c[q] - vcol[q];   // v <= 0, c >= 0 -> h >= 0
          if (h < m1) { m2 = m1; m1 = h; a1 = 8 * lane + q; }
          else if (h < m2) m2 = h;
        }
        double umin = wave_min_bcast_f64_fast(m1);
        unsigned long long bm = __ballot(m1 == umin);
        int sl = (int)__ffsll((unsigned long long)bm) - 1;
        int j1 = __builtin_amdgcn_readlane(a1, sl);   // 0-based column
        double cd = (lane == sl) ? m2 : m1;
        double usub = wave_min_bcast_f64_fast(cd);
        const bool strict = (umin < usub);
        if (strict && (j1 >> 3) == lane) {
          double dec = usub - umin;
#pragma unroll
          for (int qq = 0; qq < 8; ++qq) if (qq == (j1 & 7)) vcol[qq] -= dec;
        }
        const int powner = p_lds[j1 + 1];             // uniform read (pre-write)
        asm volatile("" ::: "memory");                // keep read before write
        const int i0 = powner - 1;
        if (lane == 0) { u_lds[i + 1] = usub; p_lds[j1 + 1] = i + 1; }
        const bool reproc = (i0 >= 0) && strict;
        if (i0 >= 0 && !strict) {
          if (lane == 0) freeL[nfree] = i0;
          nfree++;
        }
        asm volatile("s_waitcnt lgkmcnt(0)" ::: "memory");
        if (reproc) {
          i = i0;                                     // mispredict: reload
          const float4* r4m = (const float4*)(C + (size_t)i * NN);
          ca = r4m[2 * lane];
          cb = r4m[2 * lane + 1];
        } else {
          k = kn;
          if (k >= prev) break;
          i = ig; ca = nca; cb = ncb;                 // prefetch hit
        }
      }
    }
  }

  // ---- Phase 3: Dijkstra/augment for remaining free rows ----
  const int nf3 = nfree;
  // prologue: issue loads for the first free row's matrix row + potential
  int inext = (nf3 > 0) ? (freeL[0] + 1) : 1;
  float4 na, nb;
  double uu;
  {
    const float4* r4p = (const float4*)(C + (size_t)(inext - 1) * NN);
    na = r4p[2 * lane];
    nb = r4p[2 * lane + 1];
    uu = u_lds[inext];
  }

  for (int fi = 0; fi < nf3; ++fi) {
    const int i = inext;           // 1-based row (prefetched)
    if (lane == 0) p_lds[0] = i;   // augment terminator: p[0] = current row
    double minv[8], vcoff[8];
    int wayr[8], pm[8];
#pragma unroll
    for (int q = 0; q < 8; ++q) { minv[q] = 1e18; vcoff[q] = vcol[q]; wayr[q] = 0; }
#pragma unroll
    for (int q = 0; q < 8; ++q) pm[q] = p_lds[jbase + q];   // p const per Dijkstra
    int usedm = 0;
    double cum = 0.0;
    int j0 = 0;
    asm volatile("s_waitcnt lgkmcnt(0)" ::: "memory");

    while (true) {
      float c8[8] = {na.x, na.y, na.z, na.w, nb.x, nb.y, nb.z, nb.w};
      // scan: closed columns have vcoff -= 1e18 -> cur ~1e18 never beats the
      // 5e17 sentinel nor any open minv (imp stays false: wayr frozen);
      // open columns compute bit-identically to the verified (+0.0) form.
#pragma unroll
      for (int q = 0; q < 8; ++q) {
        double cur = ((double)c8[q] - uu) - vcoff[q];
        cur = (cur > 0.0) ? cur : 0.0;   // verified clamp form (never -0)
        bool imp = cur < minv[q];
        wayr[q] = imp ? j0 : wayr[q];
        minv[q] = fmin(cur, minv[q]);    // bit-exact vs cndmask select
      }
      // mask-free tree argmin over 8, carrying col + owner (strict <);
      // owner cndmasks feed only the final readlane, not the tree chain.
      double m01 = fmin(minv[0], minv[1]);
      bool   c01 = (minv[1] < minv[0]);
      int    a01 = c01 ? jbase + 1 : jbase + 0;
      int    p01 = c01 ? pm[1] : pm[0];
      double m23 = fmin(minv[2], minv[3]);
      bool   c23 = (minv[3] < minv[2]);
      int    a23 = c23 ? jbase + 3 : jbase + 2;
      int    p23 = c23 ? pm[3] : pm[2];
      double m45 = fmin(minv[4], minv[5]);
      bool   c45 = (minv[5] < minv[4]);
      int    a45 = c45 ? jbase + 5 : jbase + 4;
      int    p45 = c45 ? pm[5] : pm[4];
      double m67 = fmin(minv[6], minv[7]);
      bool   c67 = (minv[7] < minv[6]);
      int    a67 = c67 ? jbase + 7 : jbase + 6;
      int    p67 = c67 ? pm[7] : pm[6];
      double m03 = fmin(m01, m23);
      bool   c03 = (m23 < m01);
      int    a03 = c03 ? a23 : a01;
      int    p03 = c03 ? p23 : p01;
      double m47 = fmin(m45, m67);
      bool   c47 = (m67 < m45);
      int    a47 = c47 ? a67 : a45;
      int    p47 = c47 ? p67 : p45;
      bool   cf  = (m47 < m03);
      double lm  = fmin(m03, m47);
      int    la  = cf ? a47 : a03;
      int    lp  = cf ? p47 : p03;

      // ---- exact two-stage u32 reduce; stage 1 (hi) doubles as the winner
      //      prediction -> speculative next-row loads issued immediately ----
      union DU { double d; unsigned u[2]; } lv, dd;
      lv.d = lm;
      unsigned hmin = wave_min_bcast_u32(lv.u[1]);
      unsigned long long bmh = __ballot(lv.u[1] == hmin);
      int slp = (int)__ffsll(bmh) - 1;                 // predicted winner lane
      int pnf = __builtin_amdgcn_readlane(lp, slp);
      int rs = (pnf > 0) ? (pnf - 1) : 0;
      const float4* r4s = (const float4*)(C + (size_t)rs * NN);
      float4 sca = r4s[2 * lane];
      float4 scb = r4s[2 * lane + 1];
      double uus = u_lds[pnf];          // u_lds[0] defined (=0), pnf uniform

      // stage 2 (lo among hi-winners) completes the exact (delta, lane)
      unsigned lc = (lv.u[1] == hmin) ? lv.u[0] : 0xFFFFFFFFu;
      unsigned lmin = wave_min_bcast_u32(lc);
      unsigned long long bm2 = __ballot((lv.u[1] == hmin) && (lv.u[0] == lmin));
      int sl = (int)__ffsll(bm2) - 1;
      int j1 = __builtin_amdgcn_readlane(la, sl);
      int pn = __builtin_amdgcn_readlane(lp, sl);
      dd.u[0] = lmin; dd.u[1] = hmin;
      double delta = dd.d;
      cum += delta;
#pragma unroll
      for (int q = 0; q < 8; ++q) minv[q] -= delta;   // sentinels absorb delta
      j0 = j1;
      if (pn == 0) break;

      if (pn == pnf) {                 // prediction hit: loads already in flight
        na = sca; nb = scb; uu = uus;
      } else {                         // rare hi-tie mispredict: reload exact
        const float4* r4m = (const float4*)(C + (size_t)(pn - 1) * NN);
        na = r4m[2 * lane];
        nb = r4m[2 * lane + 1];
        uu = u_lds[pn];
      }

      // marking: j1 uniform -> (owner lane, slot) are scalars; owner lane
      // closes its slot (sentinel + vcoff shift); usedm bitmask records it;
      // lane 0 records rec/preg per column in LDS.
      {
        const int ow = (j1 - 1) >> 3;
        const int qs = (j1 - 1) & 7;
        const bool meb = (lane == ow);
        usedm |= meb ? (1 << qs) : 0;
#pragma unroll
        for (int q = 0; q < 8; ++q) if (qs == q) {
          minv[q]  = meb ? 5e17 : minv[q];            // loses to all open cols
          vcoff[q] = meb ? (vcoff[q] - 1e18) : vcoff[q];  // cur >= ~1e18 now
        }
        if (lane == 0) { rec_lds[j1] = cum; preg_lds[j1] = pn; }
      }
    }

    // prefetch next Dijkstra's first row during fixup/path-walk
    // (free rows are never preg and != i, so u_lds[inext] is final here)
    inext = (fi + 1 < nf3) ? (freeL[fi + 1] + 1) : 1;
    {
      const float4* r4n = (const float4*)(C + (size_t)(inext - 1) * NN);
      na = r4n[2 * lane];
      nb = r4n[2 * lane + 1];
      uu = u_lds[inext];
    }

    if (lane == 0) u_lds[i] += cum;
    asm volatile("s_waitcnt lgkmcnt(0)" ::: "memory");
#pragma unroll
    for (int q = 0; q < 8; ++q) {
      way_lds[jbase + q] = wayr[q];    // flush reg-held way for the path walk
      if ((usedm >> q) & 1) {          // closed this Dijkstra
        double d = cum - rec_lds[jbase + q];
        int pr = preg_lds[jbase + q];
        vcol[q] -= d;
        u_lds[pr] += d;   // popped rows distinct -> no conflicts
      }
    }
    asm volatile("s_waitcnt lgkmcnt(0)" ::: "memory");
    if (lane == 0) {
      int jj = j0;
      while (jj != 0) { int jp = way_lds[jj]; p_lds[jj] = p_lds[jp]; jj = jp; }
    }
    asm volatile("s_waitcnt lgkmcnt(0)" ::: "memory");
  }

  // perm = matched cols (assigned seq1 rows) ascending, then unmatched ascending
  int mask = 0, cnt = 0;
#pragma unroll
  for (int q = 0; q < 8; ++q)
    if (p_lds[jbase + q] != 0) { mask |= 1 << q; cnt++; }
  cnt_lds[lane] = cnt;
  asm volatile("s_waitcnt lgkmcnt(0)" ::: "memory");
  int pre = 0;
  for (int l = 0; l < 64; ++l) { int cl = cnt_lds[l]; if (l < lane) pre += cl; }
  int mpos = pre;
  int upos = MM + (8 * lane - pre);
#pragma unroll
  for (int q = 0; q < 8; ++q) {
    int col = 8 * lane + q;
    if ((mask >> q) & 1) perm[b * NN + mpos++] = col;
    else                 perm[b * NN + upos++] = col;
  }
}

// ---------------------------------------------------------------------------
// Gather: out[b,i,:] = seq1[b, perm[b][i], :]
// ---------------------------------------------------------------------------
__global__ __launch_bounds__(256) void gather_kernel(const float* __restrict__ s1,
                                                     const int* __restrict__ perm,
                                                     float* __restrict__ out) {
  const int bi = blockIdx.x;
  const int b = bi >> 9;
  const int src = perm[bi];
  const float4* sp = (const float4*)(s1 + ((size_t)b * NN + src) * DD);
  float4* dp = (float4*)(out + (size_t)bi * DD);
  for (int t = threadIdx.x; t < DD / 4; t += 256) dp[t] = sp[t];
}

extern "C" void kernel_launch(void* const* d_in, const int* in_sizes, int n_in,
                              void* d_out, int out_size, void* d_ws, size_t ws_size,
                              hipStream_t stream) {
  const float* s1 = (const float*)d_in[0];
  const float* s2 = (const float*)d_in[1];
  float* out = (float*)d_out;
  float* Ct = (float*)d_out;       // staged cost matrix, overwritten by gather
  int* perm = (int*)d_ws;

  dim3 cg(NN / 128, MM / 64, BB);
  cost_kernel<<<cg, 256, 0, stream>>>(s1, s2, Ct);
  jv_kernel<<<BB, 64, 0, stream>>>(Ct, perm);
  gather_kernel<<<BB * NN, 256, 0, stream>>>(s1, perm, out);
}

// Round 8
// 6426.418 us; speedup vs baseline: 1.0034x; 1.0034x over previous
//
#include <hip/hip_runtime.h>
#include <math.h>

#define BB 16
#define NN 512   // seq1 rows = columns of the transposed LSA problem
#define MM 448   // seq2 rows = rows of the transposed LSA problem
#define DD 1536

// ---------------------------------------------------------------------------
// Cost kernel: Ct[b][j][i] = ||seq1[b,i,:] - seq2[b,j,:]||  (float32)
// REVERTED to the verified R0-R6 64x64 tile (R7's 128x64 retile cost ~40us:
// acc[32] f64 = 64 VGPRs of accumulator pressure tanked occupancy).
// ---------------------------------------------------------------------------
constexpr int TK = 32;

__global__ __launch_bounds__(256) void cost_kernel(const float* __restrict__ s1,
                                                   const float* __restrict__ s2,
                                                   float* __restrict__ Ct) {
  __shared__ float As[TK][68];
  __shared__ float Bs[TK][68];
  const int b = blockIdx.z;
  const int ibase = blockIdx.x * 64;
  const int jbase = blockIdx.y * 64;
  const int tid = threadIdx.x;
  const float* s1b = s1 + ((size_t)b * NN + ibase) * DD;
  const float* s2b = s2 + ((size_t)b * MM + jbase) * DD;
  const int ix = (tid & 15) * 4;
  const int jy = (tid >> 4) * 4;
  double acc[16];
#pragma unroll
  for (int t = 0; t < 16; ++t) acc[t] = 0.0;

  for (int k0 = 0; k0 < DD; k0 += TK) {
#pragma unroll
    for (int rep = 0; rep < 2; ++rep) {
      int idx = tid + rep * 256;
      int r = idx >> 3;
      int c4 = (idx & 7) * 4;
      float4 a = *(const float4*)(s1b + (size_t)r * DD + k0 + c4);
      As[c4 + 0][r] = a.x; As[c4 + 1][r] = a.y; As[c4 + 2][r] = a.z; As[c4 + 3][r] = a.w;
      float4 bb = *(const float4*)(s2b + (size_t)r * DD + k0 + c4);
      Bs[c4 + 0][r] = bb.x; Bs[c4 + 1][r] = bb.y; Bs[c4 + 2][r] = bb.z; Bs[c4 + 3][r] = bb.w;
    }
    __syncthreads();
    float pacc[16];
#pragma unroll
    for (int t = 0; t < 16; ++t) pacc[t] = 0.f;
#pragma unroll 8
    for (int kk = 0; kk < TK; ++kk) {
      float4 av = *(const float4*)&As[kk][ix];
      float4 bv = *(const float4*)&Bs[kk][jy];
      float a[4] = {av.x, av.y, av.z, av.w};
      float bq[4] = {bv.x, bv.y, bv.z, bv.w};
#pragma unroll
      for (int t = 0; t < 4; ++t)
#pragma unroll
        for (int q = 0; q < 4; ++q) {
          float d = a[t] - bq[q];
          pacc[t * 4 + q] = fmaf(d, d, pacc[t * 4 + q]);
        }
    }
#pragma unroll
    for (int t = 0; t < 16; ++t) acc[t] += (double)pacc[t];
    __syncthreads();
  }
#pragma unroll
  for (int t = 0; t < 4; ++t)
#pragma unroll
    for (int q = 0; q < 4; ++q) {
      int i = ibase + ix + t;
      int jj = jbase + jy + q;
      float d2 = (float)acc[t * 4 + q];
      Ct[((size_t)b * MM + jj) * NN + i] = sqrtf(fmaxf(d2, 0.f));
    }
}

// ---------------------------------------------------------------------------
// Cross-lane reduction primitives (DPP shr 1/2/4/8 + bcast 15/31, readlane 63
// broadcast — control pattern verified bit-exact across passing rounds).
// ---------------------------------------------------------------------------
__device__ __forceinline__ unsigned wave_min_bcast_u32(unsigned x) {
  int v = (int)x;
#define ST(C) { int o = __builtin_amdgcn_update_dpp(-1, v, C, 0xF, 0xF, false); \
                v = ((unsigned)o < (unsigned)v) ? o : v; }
  ST(0x111) ST(0x112) ST(0x114) ST(0x118) ST(0x142) ST(0x143)
#undef ST
  return (unsigned)__builtin_amdgcn_readlane(v, 63);
}

// Exact f64 min over the wave for NONNEGATIVE doubles: bit pattern of a
// nonneg double is order-preserving as u64 -> two u32 min stages (hi, then
// lo among hi-winners). Verified bit-exact (R1/R5/R6/R7 phase 2).
__device__ __forceinline__ double wave_min_bcast_f64_fast(double x) {
  union DU { double d; unsigned u[2]; };
  DU v; v.d = x;
  unsigned hmin = wave_min_bcast_u32(v.u[1]);
  unsigned lc = (v.u[1] == hmin) ? v.u[0] : 0xFFFFFFFFu;
  unsigned lmin = wave_min_bcast_u32(lc);
  DU r; r.u[0] = lmin; r.u[1] = hmin;
  return r.d;
}

__device__ __forceinline__ float wave_min_bcast_f32(float x) {
  union FU { float f; int i; };
  FU v; v.f = x;
  const int INFB = 0x7f7fffff;   // FLT_MAX bit pattern
#define DPP1(CTRL) { FU o; \
  o.i = __builtin_amdgcn_update_dpp(INFB, v.i, CTRL, 0xF, 0xF, false); \
  if (o.f < v.f) v.f = o.f; }
  DPP1(0x111) DPP1(0x112) DPP1(0x114) DPP1(0x118) DPP1(0x142) DPP1(0x143)
#undef DPP1
  FU r; r.i = __builtin_amdgcn_readlane(v.i, 63);
  return r.f;
}

// ---------------------------------------------------------------------------
// Full Jonker-Volgenant, ONE WAVE per batch.
// R8 = R7's jv (verified) + RUNNER-UP PREFETCH in phase 3 (depth-2
// speculation, prefetch-only, decision-identical):
//   winner(t+1) = min(runner-up(t), new values from the row scanned at t+1),
//   so after stage 1 at pop t we compute a cheap hi-word runner-up guess
//   (second lane in the hi-min ballot, else one extra u32 DPP min over
//   masked hi-words), readlane its owner from the carried lp, and prefetch
//   that row + its u. At pop t+1's adopt, pn == pnr_prev selects the
//   prefetched copy (a full pop period in flight -> zero load stall).
//   C and u_lds are constant during pops, so adopted bytes are identical
//   whichever path fires; all semantic values still come from the exact
//   two-stage u32 reduce -> decision stream bit-identical to R7.
// Phase 1/2 unchanged from R7 (4 passes, measured neutral-to-slightly-better).
// ---------------------------------------------------------------------------
__global__ __launch_bounds__(64) void jv_kernel(const float* __restrict__ Ct,
                                                int* __restrict__ perm) {
  const int b = blockIdx.x;
  const float* C = Ct + (size_t)b * MM * NN;
  __shared__ double u_lds[MM + 1];
  __shared__ int p_lds[NN + 1];
  __shared__ int way_lds[NN + 1];
  __shared__ double rec_lds[NN + 1];
  __shared__ int preg_lds[NN + 1];
  __shared__ int colOwner[NN];
  __shared__ int rowMatched[MM];
  __shared__ int freeL[MM];
  __shared__ int nfree_s;
  __shared__ int cnt_lds[64];
  const int lane = threadIdx.x;
  const int jbase = 8 * lane + 1;   // owned columns, 1-based

  if (lane == 0) u_lds[0] = 0.0;
  for (int t = lane; t <= NN; t += 64) { p_lds[t] = 0; way_lds[t] = 0; }
  for (int t = lane; t < NN; t += 64) colOwner[t] = -1;
  for (int t = lane; t < MM; t += 64) rowMatched[t] = 0;
  asm volatile("s_waitcnt lgkmcnt(0)" ::: "memory");

  // ---- Phase 1: row reduction + greedy claim (depth-2 prefetch) ----
  {
    const float4* r40 = (const float4*)(C);
    const float4* r41 = (const float4*)(C + (size_t)NN);
    float4 ca = r40[2 * lane], cb = r40[2 * lane + 1];
    float4 na = r41[2 * lane], nb = r41[2 * lane + 1];
    for (int r = 0; r < MM; ++r) {
      int rp = (r + 2 < MM) ? (r + 2) : (MM - 1);
      const float4* r4n = (const float4*)(C + (size_t)rp * NN);
      float4 pa = r4n[2 * lane], pb = r4n[2 * lane + 1];
      float c[8] = {ca.x, ca.y, ca.z, ca.w, cb.x, cb.y, cb.z, cb.w};
      float lm = 1e30f; int la = 0;
#pragma unroll
      for (int q = 0; q < 8; ++q)
        if (c[q] < lm) { lm = c[q]; la = 8 * lane + q; }
      float rm = wave_min_bcast_f32(lm);
      unsigned long long bm = __ballot(lm == rm);
      int sl = (int)__ffsll((unsigned long long)bm) - 1;
      int jc = __builtin_amdgcn_readlane(la, sl);
      if (lane == 0) {
        u_lds[r + 1] = (double)rm;
        if (colOwner[jc] < 0) {
          colOwner[jc] = r;
          rowMatched[r] = 1;
          p_lds[jc + 1] = r + 1;
        }
      }
      ca = na; cb = nb; na = pa; nb = pb;
    }
  }
  double vcol[8];
#pragma unroll
  for (int q = 0; q < 8; ++q) vcol[q] = 0.0;
  asm volatile("s_waitcnt lgkmcnt(0)" ::: "memory");

  // ---- build free list (ascending) ----
  if (lane == 0) {
    int n = 0;
    for (int r = 0; r < MM; ++r) if (!rowMatched[r]) freeL[n++] = r;
    nfree_s = n;
  }
  asm volatile("s_waitcnt lgkmcnt(0)" ::: "memory");
  int nfree = nfree_s;   // same LDS addr in all lanes -> uniform

  // ---- Phase 2: augmenting row reduction, 4 passes (next-row prefetch) ----
  for (int pass = 0; pass < 4; ++pass) {
    int prev = nfree; nfree = 0; int k = 0;
    if (prev == 0) continue;
    int i = freeL[0];                                   // uniform LDS read
    {
      const float4* r4p = (const float4*)(C + (size_t)i * NN);
      float4 ca = r4p[2 * lane];
      float4 cb = r4p[2 * lane + 1];
      while (true) {
        const int kn = k + 1;
        const int ig = (kn < prev) ? freeL[kn] : 0;     // uniform prefetch guess
        const float4* r4n = (const float4*)(C + (size_t)ig * NN);
        float4 nca = r4n[2 * lane];
        float4 ncb = r4n[2 * lane + 1];

        float c[8] = {ca.x, ca.y, ca.z, ca.w, cb.x, cb.y, cb.z, cb.w};
        double m1 = 1e18, m2 = 1e18; int a1 = 0;
#pragma unroll
        for (int q = 0; q < 8; ++q) {
          double h = (double)c[q] - vcol[q];   // v <= 0, c >= 0 -> h >= 0
          if (h < m1) { m2 = m1; m1 = h; a1 = 8 * lane + q; }
          else if (h < m2) m2 = h;
        }
        double umin = wave_min_bcast_f64_fast(m1);
        unsigned long long bm = __ballot(m1 == umin);
        int sl = (int)__ffsll((unsigned long long)bm) - 1;
        int j1 = __builtin_amdgcn_readlane(a1, sl);   // 0-based column
        double cd = (lane == sl) ? m2 : m1;
        double usub = wave_min_bcast_f64_fast(cd);
        const bool strict = (umin < usub);
        if (strict && (j1 >> 3) == lane) {
          double dec = usub - umin;
#pragma unroll
          for (int qq = 0; qq < 8; ++qq) if (qq == (j1 & 7)) vcol[qq] -= dec;
        }
        const int powner = p_lds[j1 + 1];             // uniform read (pre-write)
        asm volatile("" ::: "memory");                // keep read before write
        const int i0 = powner - 1;
        if (lane == 0) { u_lds[i + 1] = usub; p_lds[j1 + 1] = i + 1; }
        const bool reproc = (i0 >= 0) && strict;
        if (i0 >= 0 && !strict) {
          if (lane == 0) freeL[nfree] = i0;
          nfree++;
        }
        asm volatile("s_waitcnt lgkmcnt(0)" ::: "memory");
        if (reproc) {
          i = i0;                                     // mispredict: reload
          const float4* r4m = (const float4*)(C + (size_t)i * NN);
          ca = r4m[2 * lane];
          cb = r4m[2 * lane + 1];
        } else {
          k = kn;
          if (k >= prev) break;
          i = ig; ca = nca; cb = ncb;                 // prefetch hit
        }
      }
    }
  }

  // ---- Phase 3: Dijkstra/augment for remaining free rows ----
  const int nf3 = nfree;
  // prologue: issue loads for the first free row's matrix row + potential
  int inext = (nf3 > 0) ? (freeL[0] + 1) : 1;
  float4 na, nb;
  double uu;
  {
    const float4* r4p = (const float4*)(C + (size_t)(inext - 1) * NN);
    na = r4p[2 * lane];
    nb = r4p[2 * lane + 1];
    uu = u_lds[inext];
  }

  for (int fi = 0; fi < nf3; ++fi) {
    const int i = inext;           // 1-based row (prefetched)
    if (lane == 0) p_lds[0] = i;   // augment terminator: p[0] = current row
    double minv[8], vcoff[8];
    int wayr[8], pm[8];
#pragma unroll
    for (int q = 0; q < 8; ++q) { minv[q] = 1e18; vcoff[q] = vcol[q]; wayr[q] = 0; }
#pragma unroll
    for (int q = 0; q < 8; ++q) pm[q] = p_lds[jbase + q];   // p const per Dijkstra
    int usedm = 0;
    double cum = 0.0;
    int j0 = 0;
    // runner-up prefetch state (issued at pop t, consumed at pop t+1)
    int pnr_prev = -1;
    float4 rpa = na, rpb = nb;
    double upr = 0.0;
    asm volatile("s_waitcnt lgkmcnt(0)" ::: "memory");

    while (true) {
      float c8[8] = {na.x, na.y, na.z, na.w, nb.x, nb.y, nb.z, nb.w};
      // scan: closed columns have vcoff -= 1e18 -> cur ~1e18 never beats the
      // 5e17 sentinel nor any open minv (imp stays false: wayr frozen);
      // open columns compute bit-identically to the verified (+0.0) form.
#pragma unroll
      for (int q = 0; q < 8; ++q) {
        double cur = ((double)c8[q] - uu) - vcoff[q];
        cur = (cur > 0.0) ? cur : 0.0;   // verified clamp form (never -0)
        bool imp = cur < minv[q];
        wayr[q] = imp ? j0 : wayr[q];
        minv[q] = fmin(cur, minv[q]);    // bit-exact vs cndmask select
      }
      // mask-free tree argmin over 8, carrying col + owner (strict <);
      // owner cndmasks feed only the final readlane, not the tree chain.
      double m01 = fmin(minv[0], minv[1]);
      bool   c01 = (minv[1] < minv[0]);
      int    a01 = c01 ? jbase + 1 : jbase + 0;
      int    p01 = c01 ? pm[1] : pm[0];
      double m23 = fmin(minv[2], minv[3]);
      bool   c23 = (minv[3] < minv[2]);
      int    a23 = c23 ? jbase + 3 : jbase + 2;
      int    p23 = c23 ? pm[3] : pm[2];
      double m45 = fmin(minv[4], minv[5]);
      bool   c45 = (minv[5] < minv[4]);
      int    a45 = c45 ? jbase + 5 : jbase + 4;
      int    p45 = c45 ? pm[5] : pm[4];
      double m67 = fmin(minv[6], minv[7]);
      bool   c67 = (minv[7] < minv[6]);
      int    a67 = c67 ? jbase + 7 : jbase + 6;
      int    p67 = c67 ? pm[7] : pm[6];
      double m03 = fmin(m01, m23);
      bool   c03 = (m23 < m01);
      int    a03 = c03 ? a23 : a01;
      int    p03 = c03 ? p23 : p01;
      double m47 = fmin(m45, m67);
      bool   c47 = (m67 < m45);
      int    a47 = c47 ? a67 : a45;
      int    p47 = c47 ? p67 : p45;
      bool   cf  = (m47 < m03);
      double lm  = fmin(m03, m47);
      int    la  = cf ? a47 : a03;
      int    lp  = cf ? p47 : p03;

      // ---- exact two-stage u32 reduce; stage 1 (hi) doubles as the winner
      //      prediction -> speculative next-row loads issued immediately ----
      union DU { double d; unsigned u[2]; } lv, dd;
      lv.d = lm;
      unsigned hmin = wave_min_bcast_u32(lv.u[1]);
      unsigned long long bmh = __ballot(lv.u[1] == hmin);
      int slp = (int)__ffsll(bmh) - 1;                 // predicted winner lane
      int pnf = __builtin_amdgcn_readlane(lp, slp);
      int rs = (pnf > 0) ? (pnf - 1) : 0;
      const float4* r4s = (const float4*)(C + (size_t)rs * NN);
      float4 sca = r4s[2 * lane];
      float4 scb = r4s[2 * lane + 1];
      double uus = u_lds[pnf];          // u_lds[0] defined (=0), pnf uniform

      // stage 2 (lo among hi-winners) completes the exact (delta, lane)
      unsigned lc = (lv.u[1] == hmin) ? lv.u[0] : 0xFFFFFFFFu;
      unsigned lmin = wave_min_bcast_u32(lc);
      unsigned long long bm2 = __ballot((lv.u[1] == hmin) && (lv.u[0] == lmin));
      int sl = (int)__ffsll(bm2) - 1;
      int j1 = __builtin_amdgcn_readlane(la, sl);
      int pn = __builtin_amdgcn_readlane(lp, sl);
      dd.u[0] = lmin; dd.u[1] = hmin;
      double delta = dd.d;
      cum += delta;
#pragma unroll
      for (int q = 0; q < 8; ++q) minv[q] -= delta;   // sentinels absorb delta
      j0 = j1;
      if (pn == 0) break;

      // adopt: prefer the runner-up prefetch from the PREVIOUS pop (a full
      // pop period in flight -> no stall), else this pop's winner-spec load,
      // else reload. Bytes identical whichever path fires (C, u_lds const).
      if (pn == pnr_prev) {
        na = rpa; nb = rpb; uu = upr;
      } else if (pn == pnf) {
        na = sca; nb = scb; uu = uus;
      } else {
        const float4* r4m = (const float4*)(C + (size_t)(pn - 1) * NN);
        na = r4m[2 * lane];
        nb = r4m[2 * lane + 1];
        uu = u_lds[pn];
      }

      // ---- runner-up prefetch for the NEXT pop (prefetch-only guess):
      // second lane sharing hmin, else the lane at the 2nd-distinct hi-word.
      {
        unsigned long long bmh2 = bmh & (bmh - 1);
        unsigned hmasked = (lv.u[1] == hmin) ? 0xFFFFFFFFu : lv.u[1];
        unsigned hmin2 = wave_min_bcast_u32(hmasked);
        unsigned long long bmr = (bmh2 != 0ull) ? bmh2
                                                : __ballot(hmasked == hmin2);
        int slr = (int)__ffsll(bmr) - 1;
        int pnr = __builtin_amdgcn_readlane(lp, slr);
        int rr = (pnr > 0) ? (pnr - 1) : 0;
        const float4* r4r = (const float4*)(C + (size_t)rr * NN);
        rpa = r4r[2 * lane];
        rpb = r4r[2 * lane + 1];
        upr = u_lds[pnr];               // u_lds constant during pops
        pnr_prev = pnr;
      }

      // marking: j1 uniform -> (owner lane, slot) are scalars; owner lane
      // closes its slot (sentinel + vcoff shift); usedm bitmask records it;
      // lane 0 records rec/preg per column in LDS.
      {
        const int ow = (j1 - 1) >> 3;
        const int qs = (j1 - 1) & 7;
        const bool meb = (lane == ow);
        usedm |= meb ? (1 << qs) : 0;
#pragma unroll
        for (int q = 0; q < 8; ++q) if (qs == q) {
          minv[q]  = meb ? 5e17 : minv[q];            // loses to all open cols
          vcoff[q] = meb ? (vcoff[q] - 1e18) : vcoff[q];  // cur >= ~1e18 now
        }
        if (lane == 0) { rec_lds[j1] = cum; preg_lds[j1] = pn; }
      }
    }

    // prefetch next Dijkstra's first row during fixup/path-walk
    // (free rows are never preg and != i, so u_lds[inext] is final here)
    inext = (fi + 1 < nf3) ? (freeL[fi + 1] + 1) : 1;
    {
      const float4* r4n = (const float4*)(C + (size_t)(inext - 1) * NN);
      na = r4n[2 * lane];
      nb = r4n[2 * lane + 1];
      uu = u_lds[inext];
    }

    if (lane == 0) u_lds[i] += cum;
    asm volatile("s_waitcnt lgkmcnt(0)" ::: "memory");
#pragma unroll
    for (int q = 0; q < 8; ++q) {
      way_lds[jbase + q] = wayr[q];    // flush reg-held way for the path walk
      if ((usedm >> q) & 1) {          // closed this Dijkstra
        double d = cum - rec_lds[jbase + q];
        int pr = preg_lds[jbase + q];
        vcol[q] -= d;
        u_lds[pr] += d;   // popped rows distinct -> no conflicts
      }
    }
    asm volatile("s_waitcnt lgkmcnt(0)" ::: "memory");
    if (lane == 0) {
      int jj = j0;
      while (jj != 0) { int jp = way_lds[jj]; p_lds[jj] = p_lds[jp]; jj = jp; }
    }
    asm volatile("s_waitcnt lgkmcnt(0)" ::: "memory");
  }

  // perm = matched cols (assigned seq1 rows) ascending, then unmatched ascending
  int mask = 0, cnt = 0;
#pragma unroll
  for (int q = 0; q < 8; ++q)
    if (p_lds[jbase + q] != 0) { mask |= 1 << q; cnt++; }
  cnt_lds[lane] = cnt;
  asm volatile("s_waitcnt lgkmcnt(0)" ::: "memory");
  int pre = 0;
  for (int l = 0; l < 64; ++l) { int cl = cnt_lds[l]; if (l < lane) pre += cl; }
  int mpos = pre;
  int upos = MM + (8 * lane - pre);
#pragma unroll
  for (int q = 0; q < 8; ++q) {
    int col = 8 * lane + q;
    if ((mask >> q) & 1) perm[b * NN + mpos++] = col;
    else                 perm[b * NN + upos++] = col;
  }
}

// ---------------------------------------------------------------------------
// Gather: out[b,i,:] = seq1[b, perm[b][i], :]
// ---------------------------------------------------------------------------
__global__ __launch_bounds__(256) void gather_kernel(const float* __restrict__ s1,
                                                     const int* __restrict__ perm,
                                                     float* __restrict__ out) {
  const int bi = blockIdx.x;
  const int b = bi >> 9;
  const int src = perm[bi];
  const float4* sp = (const float4*)(s1 + ((size_t)b * NN + src) * DD);
  float4* dp = (float4*)(out + (size_t)bi * DD);
  for (int t = threadIdx.x; t < DD / 4; t += 256) dp[t] = sp[t];
}

extern "C" void kernel_launch(void* const* d_in, const int* in_sizes, int n_in,
                              void* d_out, int out_size, void* d_ws, size_t ws_size,
                              hipStream_t stream) {
  const float* s1 = (const float*)d_in[0];
  const float* s2 = (const float*)d_in[1];
  float* out = (float*)d_out;
  float* Ct = (float*)d_out;       // staged cost matrix, overwritten by gather
  int* perm = (int*)d_ws;

  dim3 cg(NN / 64, MM / 64, BB);
  cost_kernel<<<cg, 256, 0, stream>>>(s1, s2, Ct);
  jv_kernel<<<BB, 64, 0, stream>>>(Ct, perm);
  gather_kernel<<<BB * NN, 256, 0, stream>>>(s1, perm, out);
}

// Round 9
// 6394.851 us; speedup vs baseline: 1.0084x; 1.0049x over previous
//
#include <hip/hip_runtime.h>
#include <math.h>

#define BB 16
#define NN 512   // seq1 rows = columns of the transposed LSA problem
#define MM 448   // seq2 rows = rows of the transposed LSA problem
#define DD 1536

// ---------------------------------------------------------------------------
// Cost kernel: Ct[b][j][i] = ||seq1[b,i,:] - seq2[b,j,:]||  (float32)
// R9: single-barrier double-buffered LDS. Next tile's global loads are
// issued BEFORE computing the current tile (latency hides under the FMAs);
// the LDS write goes to the other buffer, so ONE barrier per tile suffices
// (iter t reads buf[p] & writes buf[1-p]; t+1's writes to buf[p] come after
// t's barrier, and t's reads precede it). Math untouched: same k0/kk order,
// same fmaf chains, same f64 outer accumulate -> Ct BIT-IDENTICAL.
// ---------------------------------------------------------------------------
constexpr int TK = 32;

__global__ __launch_bounds__(256) void cost_kernel(const float* __restrict__ s1,
                                                   const float* __restrict__ s2,
                                                   float* __restrict__ Ct) {
  __shared__ float As[2][TK][68];
  __shared__ float Bs[2][TK][68];
  const int b = blockIdx.z;
  const int ibase = blockIdx.x * 64;
  const int jbase = blockIdx.y * 64;
  const int tid = threadIdx.x;
  const float* s1b = s1 + ((size_t)b * NN + ibase) * DD;
  const float* s2b = s2 + ((size_t)b * MM + jbase) * DD;
  const int ix = (tid & 15) * 4;
  const int jy = (tid >> 4) * 4;
  // staging indices (rep0 = tid, rep1 = tid + 256)
  const int r0 = tid >> 3,          c40 = (tid & 7) * 4;
  const int r1 = (tid + 256) >> 3,  c41 = ((tid + 256) & 7) * 4;
  double acc[16];
#pragma unroll
  for (int t = 0; t < 16; ++t) acc[t] = 0.0;

  // preload tile 0 into buffer 0
  {
    float4 a0 = *(const float4*)(s1b + (size_t)r0 * DD + c40);
    float4 a1 = *(const float4*)(s1b + (size_t)r1 * DD + c41);
    float4 b0 = *(const float4*)(s2b + (size_t)r0 * DD + c40);
    float4 b1 = *(const float4*)(s2b + (size_t)r1 * DD + c41);
    As[0][c40 + 0][r0] = a0.x; As[0][c40 + 1][r0] = a0.y;
    As[0][c40 + 2][r0] = a0.z; As[0][c40 + 3][r0] = a0.w;
    As[0][c41 + 0][r1] = a1.x; As[0][c41 + 1][r1] = a1.y;
    As[0][c41 + 2][r1] = a1.z; As[0][c41 + 3][r1] = a1.w;
    Bs[0][c40 + 0][r0] = b0.x; Bs[0][c40 + 1][r0] = b0.y;
    Bs[0][c40 + 2][r0] = b0.z; Bs[0][c40 + 3][r0] = b0.w;
    Bs[0][c41 + 0][r1] = b1.x; Bs[0][c41 + 1][r1] = b1.y;
    Bs[0][c41 + 2][r1] = b1.z; Bs[0][c41 + 3][r1] = b1.w;
  }
  __syncthreads();

  int cur = 0;
  for (int k0 = 0; k0 < DD; k0 += TK) {
    // issue next tile's global loads NOW (clamped on last iter; discarded)
    const int kp = (k0 + TK < DD) ? (k0 + TK) : k0;
    float4 na0 = *(const float4*)(s1b + (size_t)r0 * DD + kp + c40);
    float4 na1 = *(const float4*)(s1b + (size_t)r1 * DD + kp + c41);
    float4 nb0 = *(const float4*)(s2b + (size_t)r0 * DD + kp + c40);
    float4 nb1 = *(const float4*)(s2b + (size_t)r1 * DD + kp + c41);

    // compute current tile from buf[cur] (identical FMA chains)
    float pacc[16];
#pragma unroll
    for (int t = 0; t < 16; ++t) pacc[t] = 0.f;
#pragma unroll 8
    for (int kk = 0; kk < TK; ++kk) {
      float4 av = *(const float4*)&As[cur][kk][ix];
      float4 bv = *(const float4*)&Bs[cur][kk][jy];
      float a[4] = {av.x, av.y, av.z, av.w};
      float bq[4] = {bv.x, bv.y, bv.z, bv.w};
#pragma unroll
      for (int t = 0; t < 4; ++t)
#pragma unroll
        for (int q = 0; q < 4; ++q) {
          float d = a[t] - bq[q];
          pacc[t * 4 + q] = fmaf(d, d, pacc[t * 4 + q]);
        }
    }
#pragma unroll
    for (int t = 0; t < 16; ++t) acc[t] += (double)pacc[t];

    // write next tile into the OTHER buffer (no reader conflict), then the
    // single barrier fences both the writes and the buf-swap.
    const int nxt = cur ^ 1;
    As[nxt][c40 + 0][r0] = na0.x; As[nxt][c40 + 1][r0] = na0.y;
    As[nxt][c40 + 2][r0] = na0.z; As[nxt][c40 + 3][r0] = na0.w;
    As[nxt][c41 + 0][r1] = na1.x; As[nxt][c41 + 1][r1] = na1.y;
    As[nxt][c41 + 2][r1] = na1.z; As[nxt][c41 + 3][r1] = na1.w;
    Bs[nxt][c40 + 0][r0] = nb0.x; Bs[nxt][c40 + 1][r0] = nb0.y;
    Bs[nxt][c40 + 2][r0] = nb0.z; Bs[nxt][c40 + 3][r0] = nb0.w;
    Bs[nxt][c41 + 0][r1] = nb1.x; Bs[nxt][c41 + 1][r1] = nb1.y;
    Bs[nxt][c41 + 2][r1] = nb1.z; Bs[nxt][c41 + 3][r1] = nb1.w;
    __syncthreads();
    cur = nxt;
  }
#pragma unroll
  for (int t = 0; t < 4; ++t)
#pragma unroll
    for (int q = 0; q < 4; ++q) {
      int i = ibase + ix + t;
      int jj = jbase + jy + q;
      float d2 = (float)acc[t * 4 + q];
      Ct[((size_t)b * MM + jj) * NN + i] = sqrtf(fmaxf(d2, 0.f));
    }
}

// ---------------------------------------------------------------------------
// Cross-lane reduction primitives (DPP shr 1/2/4/8 + bcast 15/31, readlane 63
// broadcast — control pattern verified bit-exact across passing rounds).
// ---------------------------------------------------------------------------
__device__ __forceinline__ unsigned wave_min_bcast_u32(unsigned x) {
  int v = (int)x;
#define ST(C) { int o = __builtin_amdgcn_update_dpp(-1, v, C, 0xF, 0xF, false); \
                v = ((unsigned)o < (unsigned)v) ? o : v; }
  ST(0x111) ST(0x112) ST(0x114) ST(0x118) ST(0x142) ST(0x143)
#undef ST
  return (unsigned)__builtin_amdgcn_readlane(v, 63);
}

// Exact f64 min over the wave for NONNEGATIVE doubles: bit pattern of a
// nonneg double is order-preserving as u64 -> two u32 min stages (hi, then
// lo among hi-winners). Verified bit-exact (R1/R5/R6/R7/R8 phase 2).
__device__ __forceinline__ double wave_min_bcast_f64_fast(double x) {
  union DU { double d; unsigned u[2]; };
  DU v; v.d = x;
  unsigned hmin = wave_min_bcast_u32(v.u[1]);
  unsigned lc = (v.u[1] == hmin) ? v.u[0] : 0xFFFFFFFFu;
  unsigned lmin = wave_min_bcast_u32(lc);
  DU r; r.u[0] = lmin; r.u[1] = hmin;
  return r.d;
}

__device__ __forceinline__ float wave_min_bcast_f32(float x) {
  union FU { float f; int i; };
  FU v; v.f = x;
  const int INFB = 0x7f7fffff;   // FLT_MAX bit pattern
#define DPP1(CTRL) { FU o; \
  o.i = __builtin_amdgcn_update_dpp(INFB, v.i, CTRL, 0xF, 0xF, false); \
  if (o.f < v.f) v.f = o.f; }
  DPP1(0x111) DPP1(0x112) DPP1(0x114) DPP1(0x118) DPP1(0x142) DPP1(0x143)
#undef DPP1
  FU r; r.i = __builtin_amdgcn_readlane(v.i, 63);
  return r.f;
}

// ---------------------------------------------------------------------------
// Full Jonker-Volgenant, ONE WAVE per batch. VERBATIM from R8 (passed,
// absmax 0). Six structurally different pop loops all measured 5990+-15us:
// the pop period is pinned by the serial f64 column scan (half-rate f64)
// plus two dependent 6-deep DPP reduce chains — a serialization floor for
// the one-wave formulation, not a hardware roofline.
// ---------------------------------------------------------------------------
__global__ __launch_bounds__(64) void jv_kernel(const float* __restrict__ Ct,
                                                int* __restrict__ perm) {
  const int b = blockIdx.x;
  const float* C = Ct + (size_t)b * MM * NN;
  __shared__ double u_lds[MM + 1];
  __shared__ int p_lds[NN + 1];
  __shared__ int way_lds[NN + 1];
  __shared__ double rec_lds[NN + 1];
  __shared__ int preg_lds[NN + 1];
  __shared__ int colOwner[NN];
  __shared__ int rowMatched[MM];
  __shared__ int freeL[MM];
  __shared__ int nfree_s;
  __shared__ int cnt_lds[64];
  const int lane = threadIdx.x;
  const int jbase = 8 * lane + 1;   // owned columns, 1-based

  if (lane == 0) u_lds[0] = 0.0;
  for (int t = lane; t <= NN; t += 64) { p_lds[t] = 0; way_lds[t] = 0; }
  for (int t = lane; t < NN; t += 64) colOwner[t] = -1;
  for (int t = lane; t < MM; t += 64) rowMatched[t] = 0;
  asm volatile("s_waitcnt lgkmcnt(0)" ::: "memory");

  // ---- Phase 1: row reduction + greedy claim (depth-2 prefetch) ----
  {
    const float4* r40 = (const float4*)(C);
    const float4* r41 = (const float4*)(C + (size_t)NN);
    float4 ca = r40[2 * lane], cb = r40[2 * lane + 1];
    float4 na = r41[2 * lane], nb = r41[2 * lane + 1];
    for (int r = 0; r < MM; ++r) {
      int rp = (r + 2 < MM) ? (r + 2) : (MM - 1);
      const float4* r4n = (const float4*)(C + (size_t)rp * NN);
      float4 pa = r4n[2 * lane], pb = r4n[2 * lane + 1];
      float c[8] = {ca.x, ca.y, ca.z, ca.w, cb.x, cb.y, cb.z, cb.w};
      float lm = 1e30f; int la = 0;
#pragma unroll
      for (int q = 0; q < 8; ++q)
        if (c[q] < lm) { lm = c[q]; la = 8 * lane + q; }
      float rm = wave_min_bcast_f32(lm);
      unsigned long long bm = __ballot(lm == rm);
      int sl = (int)__ffsll((unsigned long long)bm) - 1;
      int jc = __builtin_amdgcn_readlane(la, sl);
      if (lane == 0) {
        u_lds[r + 1] = (double)rm;
        if (colOwner[jc] < 0) {
          colOwner[jc] = r;
          rowMatched[r] = 1;
          p_lds[jc + 1] = r + 1;
        }
      }
      ca = na; cb = nb; na = pa; nb = pb;
    }
  }
  double vcol[8];
#pragma unroll
  for (int q = 0; q < 8; ++q) vcol[q] = 0.0;
  asm volatile("s_waitcnt lgkmcnt(0)" ::: "memory");

  // ---- build free list (ascending) ----
  if (lane == 0) {
    int n = 0;
    for (int r = 0; r < MM; ++r) if (!rowMatched[r]) freeL[n++] = r;
    nfree_s = n;
  }
  asm volatile("s_waitcnt lgkmcnt(0)" ::: "memory");
  int nfree = nfree_s;   // same LDS addr in all lanes -> uniform

  // ---- Phase 2: augmenting row reduction, 4 passes (next-row prefetch) ----
  for (int pass = 0; pass < 4; ++pass) {
    int prev = nfree; nfree = 0; int k = 0;
    if (prev == 0) continue;
    int i = freeL[0];                                   // uniform LDS read
    {
      const float4* r4p = (const float4*)(C + (size_t)i * NN);
      float4 ca = r4p[2 * lane];
      float4 cb = r4p[2 * lane + 1];
      while (true) {
        const int kn = k + 1;
        const int ig = (kn < prev) ? freeL[kn] : 0;     // uniform prefetch guess
        const float4* r4n = (const float4*)(C + (size_t)ig * NN);
        float4 nca = r4n[2 * lane];
        float4 ncb = r4n[2 * lane + 1];

        float c[8] = {ca.x, ca.y, ca.z, ca.w, cb.x, cb.y, cb.z, cb.w};
        double m1 = 1e18, m2 = 1e18; int a1 = 0;
#pragma unroll
        for (int q = 0; q < 8; ++q) {
          double h = (double)c[q] - vcol[q];   // v <= 0, c >= 0 -> h >= 0
          if (h < m1) { m2 = m1; m1 = h; a1 = 8 * lane + q; }
          else if (h < m2) m2 = h;
        }
        double umin = wave_min_bcast_f64_fast(m1);
        unsigned long long bm = __ballot(m1 == umin);
        int sl = (int)__ffsll((unsigned long long)bm) - 1;
        int j1 = __builtin_amdgcn_readlane(a1, sl);   // 0-based column
        double cd = (lane == sl) ? m2 : m1;
        double usub = wave_min_bcast_f64_fast(cd);
        const bool strict = (umin < usub);
        if (strict && (j1 >> 3) == lane) {
          double dec = usub - umin;
#pragma unroll
          for (int qq = 0; qq < 8; ++qq) if (qq == (j1 & 7)) vcol[qq] -= dec;
        }
        const int powner = p_lds[j1 + 1];             // uniform read (pre-write)
        asm volatile("" ::: "memory");                // keep read before write
        const int i0 = powner - 1;
        if (lane == 0) { u_lds[i + 1] = usub; p_lds[j1 + 1] = i + 1; }
        const bool reproc = (i0 >= 0) && strict;
        if (i0 >= 0 && !strict) {
          if (lane == 0) freeL[nfree] = i0;
          nfree++;
        }
        asm volatile("s_waitcnt lgkmcnt(0)" ::: "memory");
        if (reproc) {
          i = i0;                                     // mispredict: reload
          const float4* r4m = (const float4*)(C + (size_t)i * NN);
          ca = r4m[2 * lane];
          cb = r4m[2 * lane + 1];
        } else {
          k = kn;
          if (k >= prev) break;
          i = ig; ca = nca; cb = ncb;                 // prefetch hit
        }
      }
    }
  }

  // ---- Phase 3: Dijkstra/augment for remaining free rows ----
  const int nf3 = nfree;
  // prologue: issue loads for the first free row's matrix row + potential
  int inext = (nf3 > 0) ? (freeL[0] + 1) : 1;
  float4 na, nb;
  double uu;
  {
    const float4* r4p = (const float4*)(C + (size_t)(inext - 1) * NN);
    na = r4p[2 * lane];
    nb = r4p[2 * lane + 1];
    uu = u_lds[inext];
  }

  for (int fi = 0; fi < nf3; ++fi) {
    const int i = inext;           // 1-based row (prefetched)
    if (lane == 0) p_lds[0] = i;   // augment terminator: p[0] = current row
    double minv[8], vcoff[8];
    int wayr[8], pm[8];
#pragma unroll
    for (int q = 0; q < 8; ++q) { minv[q] = 1e18; vcoff[q] = vcol[q]; wayr[q] = 0; }
#pragma unroll
    for (int q = 0; q < 8; ++q) pm[q] = p_lds[jbase + q];   // p const per Dijkstra
    int usedm = 0;
    double cum = 0.0;
    int j0 = 0;
    // runner-up prefetch state (issued at pop t, consumed at pop t+1)
    int pnr_prev = -1;
    float4 rpa = na, rpb = nb;
    double upr = 0.0;
    asm volatile("s_waitcnt lgkmcnt(0)" ::: "memory");

    while (true) {
      float c8[8] = {na.x, na.y, na.z, na.w, nb.x, nb.y, nb.z, nb.w};
      // scan: closed columns have vcoff -= 1e18 -> cur ~1e18 never beats the
      // 5e17 sentinel nor any open minv (imp stays false: wayr frozen);
      // open columns compute bit-identically to the verified (+0.0) form.
#pragma unroll
      for (int q = 0; q < 8; ++q) {
        double cur = ((double)c8[q] - uu) - vcoff[q];
        cur = (cur > 0.0) ? cur : 0.0;   // verified clamp form (never -0)
        bool imp = cur < minv[q];
        wayr[q] = imp ? j0 : wayr[q];
        minv[q] = fmin(cur, minv[q]);    // bit-exact vs cndmask select
      }
      // mask-free tree argmin over 8, carrying col + owner (strict <);
      // owner cndmasks feed only the final readlane, not the tree chain.
      double m01 = fmin(minv[0], minv[1]);
      bool   c01 = (minv[1] < minv[0]);
      int    a01 = c01 ? jbase + 1 : jbase + 0;
      int    p01 = c01 ? pm[1] : pm[0];
      double m23 = fmin(minv[2], minv[3]);
      bool   c23 = (minv[3] < minv[2]);
      int    a23 = c23 ? jbase + 3 : jbase + 2;
      int    p23 = c23 ? pm[3] : pm[2];
      double m45 = fmin(minv[4], minv[5]);
      bool   c45 = (minv[5] < minv[4]);
      int    a45 = c45 ? jbase + 5 : jbase + 4;
      int    p45 = c45 ? pm[5] : pm[4];
      double m67 = fmin(minv[6], minv[7]);
      bool   c67 = (minv[7] < minv[6]);
      int    a67 = c67 ? jbase + 7 : jbase + 6;
      int    p67 = c67 ? pm[7] : pm[6];
      double m03 = fmin(m01, m23);
      bool   c03 = (m23 < m01);
      int    a03 = c03 ? a23 : a01;
      int    p03 = c03 ? p23 : p01;
      double m47 = fmin(m45, m67);
      bool   c47 = (m67 < m45);
      int    a47 = c47 ? a67 : a45;
      int    p47 = c47 ? p67 : p45;
      bool   cf  = (m47 < m03);
      double lm  = fmin(m03, m47);
      int    la  = cf ? a47 : a03;
      int    lp  = cf ? p47 : p03;

      // ---- exact two-stage u32 reduce; stage 1 (hi) doubles as the winner
      //      prediction -> speculative next-row loads issued immediately ----
      union DU { double d; unsigned u[2]; } lv, dd;
      lv.d = lm;
      unsigned hmin = wave_min_bcast_u32(lv.u[1]);
      unsigned long long bmh = __ballot(lv.u[1] == hmin);
      int slp = (int)__ffsll(bmh) - 1;                 // predicted winner lane
      int pnf = __builtin_amdgcn_readlane(lp, slp);
      int rs = (pnf > 0) ? (pnf - 1) : 0;
      const float4* r4s = (const float4*)(C + (size_t)rs * NN);
      float4 sca = r4s[2 * lane];
      float4 scb = r4s[2 * lane + 1];
      double uus = u_lds[pnf];          // u_lds[0] defined (=0), pnf uniform

      // stage 2 (lo among hi-winners) completes the exact (delta, lane)
      unsigned lc = (lv.u[1] == hmin) ? lv.u[0] : 0xFFFFFFFFu;
      unsigned lmin = wave_min_bcast_u32(lc);
      unsigned long long bm2 = __ballot((lv.u[1] == hmin) && (lv.u[0] == lmin));
      int sl = (int)__ffsll(bm2) - 1;
      int j1 = __builtin_amdgcn_readlane(la, sl);
      int pn = __builtin_amdgcn_readlane(lp, sl);
      dd.u[0] = lmin; dd.u[1] = hmin;
      double delta = dd.d;
      cum += delta;
#pragma unroll
      for (int q = 0; q < 8; ++q) minv[q] -= delta;   // sentinels absorb delta
      j0 = j1;
      if (pn == 0) break;

      // adopt: prefer the runner-up prefetch from the PREVIOUS pop (a full
      // pop period in flight -> no stall), else this pop's winner-spec load,
      // else reload. Bytes identical whichever path fires (C, u_lds const).
      if (pn == pnr_prev) {
        na = rpa; nb = rpb; uu = upr;
      } else if (pn == pnf) {
        na = sca; nb = scb; uu = uus;
      } else {
        const float4* r4m = (const float4*)(C + (size_t)(pn - 1) * NN);
        na = r4m[2 * lane];
        nb = r4m[2 * lane + 1];
        uu = u_lds[pn];
      }

      // ---- runner-up prefetch for the NEXT pop (prefetch-only guess):
      // second lane sharing hmin, else the lane at the 2nd-distinct hi-word.
      {
        unsigned long long bmh2 = bmh & (bmh - 1);
        unsigned hmasked = (lv.u[1] == hmin) ? 0xFFFFFFFFu : lv.u[1];
        unsigned hmin2 = wave_min_bcast_u32(hmasked);
        unsigned long long bmr = (bmh2 != 0ull) ? bmh2
                                                : __ballot(hmasked == hmin2);
        int slr = (int)__ffsll(bmr) - 1;
        int pnr = __builtin_amdgcn_readlane(lp, slr);
        int rr = (pnr > 0) ? (pnr - 1) : 0;
        const float4* r4r = (const float4*)(C + (size_t)rr * NN);
        rpa = r4r[2 * lane];
        rpb = r4r[2 * lane + 1];
        upr = u_lds[pnr];               // u_lds constant during pops
        pnr_prev = pnr;
      }

      // marking: j1 uniform -> (owner lane, slot) are scalars; owner lane
      // closes its slot (sentinel + vcoff shift); usedm bitmask records it;
      // lane 0 records rec/preg per column in LDS.
      {
        const int ow = (j1 - 1) >> 3;
        const int qs = (j1 - 1) & 7;
        const bool meb = (lane == ow);
        usedm |= meb ? (1 << qs) : 0;
#pragma unroll
        for (int q = 0; q < 8; ++q) if (qs == q) {
          minv[q]  = meb ? 5e17 : minv[q];            // loses to all open cols
          vcoff[q] = meb ? (vcoff[q] - 1e18) : vcoff[q];  // cur >= ~1e18 now
        }
        if (lane == 0) { rec_lds[j1] = cum; preg_lds[j1] = pn; }
      }
    }

    // prefetch next Dijkstra's first row during fixup/path-walk
    // (free rows are never preg and != i, so u_lds[inext] is final here)
    inext = (fi + 1 < nf3) ? (freeL[fi + 1] + 1) : 1;
    {
      const float4* r4n = (const float4*)(C + (size_t)(inext - 1) * NN);
      na = r4n[2 * lane];
      nb = r4n[2 * lane + 1];
      uu = u_lds[inext];
    }

    if (lane == 0) u_lds[i] += cum;
    asm volatile("s_waitcnt lgkmcnt(0)" ::: "memory");
#pragma unroll
    for (int q = 0; q < 8; ++q) {
      way_lds[jbase + q] = wayr[q];    // flush reg-held way for the path walk
      if ((usedm >> q) & 1) {          // closed this Dijkstra
        double d = cum - rec_lds[jbase + q];
        int pr = preg_lds[jbase + q];
        vcol[q] -= d;
        u_lds[pr] += d;   // popped rows distinct -> no conflicts
      }
    }
    asm volatile("s_waitcnt lgkmcnt(0)" ::: "memory");
    if (lane == 0) {
      int jj = j0;
      while (jj != 0) { int jp = way_lds[jj]; p_lds[jj] = p_lds[jp]; jj = jp; }
    }
    asm volatile("s_waitcnt lgkmcnt(0)" ::: "memory");
  }

  // perm = matched cols (assigned seq1 rows) ascending, then unmatched ascending
  int mask = 0, cnt = 0;
#pragma unroll
  for (int q = 0; q < 8; ++q)
    if (p_lds[jbase + q] != 0) { mask |= 1 << q; cnt++; }
  cnt_lds[lane] = cnt;
  asm volatile("s_waitcnt lgkmcnt(0)" ::: "memory");
  int pre = 0;
  for (int l = 0; l < 64; ++l) { int cl = cnt_lds[l]; if (l < lane) pre += cl; }
  int mpos = pre;
  int upos = MM + (8 * lane - pre);
#pragma unroll
  for (int q = 0; q < 8; ++q) {
    int col = 8 * lane + q;
    if ((mask >> q) & 1) perm[b * NN + mpos++] = col;
    else                 perm[b * NN + upos++] = col;
  }
}

// ---------------------------------------------------------------------------
// Gather: out[b,i,:] = seq1[b, perm[b][i], :]
// ---------------------------------------------------------------------------
__global__ __launch_bounds__(256) void gather_kernel(const float* __restrict__ s1,
                                                     const int* __restrict__ perm,
                                                     float* __restrict__ out) {
  const int bi = blockIdx.x;
  const int b = bi >> 9;
  const int src = perm[bi];
  const float4* sp = (const float4*)(s1 + ((size_t)b * NN + src) * DD);
  float4* dp = (float4*)(out + (size_t)bi * DD);
  for (int t = threadIdx.x; t < DD / 4; t += 256) dp[t] = sp[t];
}

extern "C" void kernel_launch(void* const* d_in, const int* in_sizes, int n_in,
                              void* d_out, int out_size, void* d_ws, size_t ws_size,
                              hipStream_t stream) {
  const float* s1 = (const float*)d_in[0];
  const float* s2 = (const float*)d_in[1];
  float* out = (float*)d_out;
  float* Ct = (float*)d_out;       // staged cost matrix, overwritten by gather
  int* perm = (int*)d_ws;

  dim3 cg(NN / 64, MM / 64, BB);
  cost_kernel<<<cg, 256, 0, stream>>>(s1, s2, Ct);
  jv_kernel<<<BB, 64, 0, stream>>>(Ct, perm);
  gather_kernel<<<BB * NN, 256, 0, stream>>>(s1, perm, out);
}